// Round 1
// baseline (196.579 us; speedup 1.0000x reference)
//
#include <hip/hip_runtime.h>
#include <math.h>

#define Bn 32
#define Cn 768
#define CRn 192
#define HWn 1024   // H*W = 32*32, contiguous innermost per (b,c)

typedef float nfloat4 __attribute__((ext_vector_type(4)));  // native vec for nt store

// ---------------- Kernel 1: squeeze (mean over HW per (b,c)) ----------------
// One WAVE per (b,c): each lane holds 4 independent float4 loads (64 B of ILP)
// before a single 6-step reduce. 6144 blocks, 4 bc per block.
__global__ __launch_bounds__(256) void se_mean(const float* __restrict__ x,
                                               float* __restrict__ s) {
    const int wid  = threadIdx.x >> 6;
    const int lane = threadIdx.x & 63;
    const int bc   = blockIdx.x * 4 + wid;

    const float4* xp = (const float4*)(x + (size_t)bc * HWn);
    float4 v0 = xp[lane];
    float4 v1 = xp[lane + 64];
    float4 v2 = xp[lane + 128];
    float4 v3 = xp[lane + 192];

    float sum = (v0.x + v0.y + v0.z + v0.w)
              + (v1.x + v1.y + v1.z + v1.w)
              + (v2.x + v2.y + v2.z + v2.w)
              + (v3.x + v3.y + v3.z + v3.w);
    #pragma unroll
    for (int off = 32; off > 0; off >>= 1) sum += __shfl_down(sum, off);
    if (lane == 0) s[bc] = sum * (1.0f / (float)HWn);
}

// ---------------- Kernel 2: h = swish(s @ w1^T + b1) ------------------------
// One WAVE per (b,j) dot of length 768: 3 coalesced float4 loads per lane,
// then wave-reduce. 1536 blocks; ~2 us.
__global__ __launch_bounds__(256) void se_h(const float* __restrict__ s,
                                            const float* __restrict__ w1,
                                            const float* __restrict__ b1,
                                            float* __restrict__ h) {
    const int wid  = threadIdx.x >> 6;
    const int lane = threadIdx.x & 63;
    const int b = blockIdx.x / (CRn / 4);           // 4 dots per block (one per wave)
    const int j = (blockIdx.x % (CRn / 4)) * 4 + wid;

    const float4* wr = (const float4*)(w1 + (size_t)j * Cn);   // 192 float4s
    const float4* sp = (const float4*)(s + (size_t)b * Cn);
    float acc = 0.0f;
    #pragma unroll
    for (int t = 0; t < 3; ++t) {
        float4 wv = wr[lane + 64 * t];
        float4 sv = sp[lane + 64 * t];
        acc += wv.x * sv.x + wv.y * sv.y + wv.z * sv.z + wv.w * sv.w;
    }
    #pragma unroll
    for (int off = 32; off > 0; off >>= 1) acc += __shfl_down(acc, off);
    if (lane == 0) {
        float v = acc + b1[j];
        h[b * CRn + j] = v / (1.0f + expf(-v));     // swish
    }
}

// ---------------- Kernel 3: fused gate + scale ------------------------------
// One WAVE per (b,c): the gate dot is computed ONCE per channel (was 4x
// redundant), and each lane owns 4 float4 x-elements whose loads are issued
// up front so the dot's shfl/exp dependency chain hides under them.
// x re-read is L3-resident from kernel 1; store is nontemporal (write-once).
__global__ __launch_bounds__(256) void se_scale_g(const float* __restrict__ x,
                                                  const float* __restrict__ h,
                                                  const float* __restrict__ w2,
                                                  const float* __restrict__ b2,
                                                  float* __restrict__ out) {
    const int wid  = threadIdx.x >> 6;
    const int lane = threadIdx.x & 63;
    const int bc   = blockIdx.x * 4 + wid;
    const int b = bc / Cn;
    const int c = bc % Cn;

    // gate-dot operands first: they head the longest dependency chain
    const float* hp = h  + (size_t)b * CRn;
    const float* wp = w2 + (size_t)c * CRn;
    float h0 = hp[lane],       w0 = wp[lane];
    float h1 = hp[lane + 64],  w1v = wp[lane + 64];
    float h2 = hp[lane + 128], w2v = wp[lane + 128];

    // streaming x loads in flight while the reduce runs
    const float4* xp = (const float4*)(x + (size_t)bc * HWn);
    float4 v0 = xp[lane];
    float4 v1 = xp[lane + 64];
    float4 v2 = xp[lane + 128];
    float4 v3 = xp[lane + 192];

    float acc = h0 * w0 + h1 * w1v + h2 * w2v;
    #pragma unroll
    for (int off = 32; off > 0; off >>= 1) acc += __shfl_xor(acc, off);
    const float g = 1.0f / (1.0f + expf(-(acc + b2[c])));

    nfloat4* op = (nfloat4*)(out + (size_t)bc * HWn);
    nfloat4 o0 = { v0.x * g, v0.y * g, v0.z * g, v0.w * g };
    nfloat4 o1 = { v1.x * g, v1.y * g, v1.z * g, v1.w * g };
    nfloat4 o2 = { v2.x * g, v2.y * g, v2.z * g, v2.w * g };
    nfloat4 o3 = { v3.x * g, v3.y * g, v3.z * g, v3.w * g };
    __builtin_nontemporal_store(o0, &op[lane]);
    __builtin_nontemporal_store(o1, &op[lane + 64]);
    __builtin_nontemporal_store(o2, &op[lane + 128]);
    __builtin_nontemporal_store(o3, &op[lane + 192]);
}

extern "C" void kernel_launch(void* const* d_in, const int* in_sizes, int n_in,
                              void* d_out, int out_size, void* d_ws, size_t ws_size,
                              hipStream_t stream) {
    const float* x  = (const float*)d_in[0];
    const float* w1 = (const float*)d_in[1];
    const float* b1 = (const float*)d_in[2];
    const float* w2 = (const float*)d_in[3];
    const float* b2 = (const float*)d_in[4];
    float* out = (float*)d_out;

    float* s = (float*)d_ws;            // [B*C]  means
    float* h = s + (size_t)Bn * Cn;     // [B*Cr] hidden activations

    se_mean   <<<Bn * Cn / 4,    256, 0, stream>>>(x, s);
    se_h      <<<Bn * (CRn / 4), 256, 0, stream>>>(s, w1, b1, h);
    se_scale_g<<<Bn * Cn / 4,    256, 0, stream>>>(x, h, w2, b2, out);
}